// Round 12
// baseline (783.578 us; speedup 1.0000x reference)
//
#include <hip/hip_runtime.h>
#include <math.h>

#define SEQ 128
#define BATCH 32
#define EDIM 300
#define HDIM 200
#define G4 800      // 4*H
#define NGATE 1600  // 2 dirs * 4 * H
#define KC 25       // 25 chunks of 8 halves = 200 k-values
#define PERSIST 16  // chunks pinned in registers (64 VGPR)
#define NLDS 4      // chunks held in LDS (51.2 KB)
#define STREAM0 (PERSIST + NLDS)   // chunks 20..24 streamed from L2
#define CHSTRIDE 6400   // halves between k-chunks in Upk: 800 rows * 8

typedef _Float16 h2t __attribute__((ext_vector_type(2)));

__device__ __forceinline__ h2t u2h(unsigned v) {
    union { unsigned u; h2t h; } c; c.u = v; return c.h;
}

// v_dot2_f32_f16: acc += a.x*b.x + a.y*b.y  (f32 accumulate)
__device__ __forceinline__ float dot2acc(h2t a, h2t b, float c) {
    return __builtin_amdgcn_fdot2(a, b, c, false);
}

// 8 halves x 8 halves -> acc (4 dot2)
__device__ __forceinline__ float dot8(uint4 u, uint4 h, float acc) {
    acc = dot2acc(u2h(u.x), u2h(h.x), acc);
    acc = dot2acc(u2h(u.y), u2h(h.y), acc);
    acc = dot2acc(u2h(u.z), u2h(h.z), acc);
    acc = dot2acc(u2h(u.w), u2h(h.w), acc);
    return acc;
}

__device__ __forceinline__ float fast_sigmoid(float x) {
    return 1.f / (1.f + __expf(-x));
}
__device__ __forceinline__ float fast_tanh(float x) {
    x = fminf(fmaxf(x, -15.f), 15.f);
    float e = __expf(2.f * x);
    return (e - 1.f) / (e + 1.f);
}

// ------------------------------------------------------------------
// K1: embedding gather  X0[t][b][e] = emb[words[b][t]][e]
// ------------------------------------------------------------------
__global__ void k_gather(const int* __restrict__ words,
                         const float* __restrict__ emb,
                         float* __restrict__ X0)
{
    int row = blockIdx.x;          // row = t*32 + b
    int t = row >> 5;
    int b = row & 31;
    int w = words[b * SEQ + t];
    const float* src = emb + (size_t)w * EDIM;
    float* dst = X0 + (size_t)row * EDIM;
    for (int e = threadIdx.x; e < EDIM; e += blockDim.x) dst[e] = src[e];
}

// ------------------------------------------------------------------
// K1b: pack Whh (2,800,200) f32 -> Upk fp16, chunk-major coalesced:
//   Upk[((d*KC + kc)*800 + r)*8 + j] = Whh[d][r][kc*8 + j]
// ------------------------------------------------------------------
__global__ void k_pack(const float* __restrict__ Whh,
                       _Float16* __restrict__ Upk)
{
    int idx = blockIdx.x * blockDim.x + threadIdx.x;   // (d*KC+kc)*800 + r
    if (idx >= 2 * KC * 800) return;
    int r  = idx % 800;
    int kc = (idx / 800) % KC;
    int d  = idx / (800 * KC);
    const float* src = Whh + ((size_t)d * G4 + r) * HDIM + kc * 8;
    _Float16* dst = Upk + (size_t)idx * 8;
#pragma unroll
    for (int j = 0; j < 8; ++j) dst[j] = (_Float16)src[j];
}

// ------------------------------------------------------------------
// K2/K4: C[M x N] = A[M x K] @ B[N x K]^T + bias[N]   (f32, tiled)
// ------------------------------------------------------------------
#define BM 64
#define BN 64
#define BK 32
#define LDT 72

__global__ __launch_bounds__(256)
void k_gemm_bias(const float* __restrict__ A,
                 const float* __restrict__ Bw,
                 const float* __restrict__ bias,
                 float* __restrict__ C,
                 int M, int N, int K)
{
    __shared__ __align__(16) float As[BK][LDT];
    __shared__ __align__(16) float Bs[BK][LDT];
    int tid = threadIdx.x;
    int tx = tid & 15, ty = tid >> 4;
    int bm = blockIdx.y * BM, bn = blockIdx.x * BN;
    float acc[4][4] = {};
    for (int k0 = 0; k0 < K; k0 += BK) {
#pragma unroll
        for (int i = 0; i < 8; ++i) {
            int idx = i * 256 + tid;
            int m = idx >> 5, k = idx & 31;
            bool ok = (k0 + k) < K;
            As[k][m] = ok ? A[(size_t)(bm + m) * K + k0 + k] : 0.f;
            Bs[k][m] = ok ? Bw[(size_t)(bn + m) * K + k0 + k] : 0.f;
        }
        __syncthreads();
#pragma unroll
        for (int kk = 0; kk < BK; ++kk) {
            float4 av = *(const float4*)&As[kk][ty * 4];
            float4 bv = *(const float4*)&Bs[kk][tx * 4];
            float a0 = av.x, a1 = av.y, a2 = av.z, a3 = av.w;
            float b0 = bv.x, b1 = bv.y, b2 = bv.z, b3 = bv.w;
            acc[0][0] += a0 * b0; acc[0][1] += a0 * b1; acc[0][2] += a0 * b2; acc[0][3] += a0 * b3;
            acc[1][0] += a1 * b0; acc[1][1] += a1 * b1; acc[1][2] += a1 * b2; acc[1][3] += a1 * b3;
            acc[2][0] += a2 * b0; acc[2][1] += a2 * b1; acc[2][2] += a2 * b2; acc[2][3] += a2 * b3;
            acc[3][0] += a3 * b0; acc[3][1] += a3 * b1; acc[3][2] += a3 * b2; acc[3][3] += a3 * b3;
        }
        __syncthreads();
    }
#pragma unroll
    for (int i = 0; i < 4; ++i) {
        int m = bm + ty * 4 + i;
#pragma unroll
        for (int j = 0; j < 4; ++j) {
            int n = bn + tx * 4 + j;
            C[(size_t)m * N + n] = acc[i][j] + bias[n];
        }
    }
}

// ------------------------------------------------------------------
// K3/K5: recurrent BiLSTM layer.
// U placement: 16 chunks PINNED in VGPRs via opaque asm on each
// 32-bit component (128-bit tied operands are unsupported -> pin
// x/y/z/w separately). Compiler cannot rematerialize an asm output,
// so the loads cannot sink into the loop (R6 failure mode); a spill
// would show as WRITE_SIZE >> 6.5 MB (tripwire).
// 4 chunks in LDS, 5 streamed from L2 (64 KB/step vs R6's 268 KB).
// __launch_bounds__(832, 4): 13 waves spread 4/3/3/3 -> 128-VGPR
// budget (R6 evidence: default heuristic targets 2 blocks/CU = 64).
// ------------------------------------------------------------------
#define REPP(X) X(0) X(1) X(2) X(3) X(4) X(5) X(6) X(7) \
                X(8) X(9) X(10) X(11) X(12) X(13) X(14) X(15)

__global__ __launch_bounds__(832, 4)
void k_lstm(const float* __restrict__ Xg,
            const _Float16* __restrict__ Upk,  // (2, KC, 800, 8) halves
            float* __restrict__ Hout)
{
    int blk = blockIdx.x;      // 0..63
    int d = blk >> 5;          // direction
    int b = blk & 31;          // batch
    int r = threadIdx.x;       // gate row
    int rr = (r < G4) ? r : (G4 - 1);   // clamped

    __shared__ __align__(16) _Float16 hbuf[2][HDIM];
    __shared__ float g_lds[G4];
    __shared__ __align__(16) _Float16 lds_u[NLDS][800][8];  // 51.2 KB

    const _Float16* up_ptr = Upk + ((size_t)d * KC * 800 + rr) * 8;

    // persistent chunks 0..15, pinned per 32-bit component
#define PDECL(i) uint4 p##i = *(const uint4*)(up_ptr + (size_t)(i) * CHSTRIDE); \
                 asm volatile("" : "+v"(p##i.x), "+v"(p##i.y),                  \
                                   "+v"(p##i.z), "+v"(p##i.w));
    REPP(PDECL)
#undef PDECL

    // LDS chunks 16..19: each worker writes its own row
    if (r < G4) {
#pragma unroll
        for (int j = 0; j < NLDS; ++j)
            *(uint4*)&lds_u[j][r][0] =
                *(const uint4*)(up_ptr + (size_t)(PERSIST + j) * CHSTRIDE);
    }

    if (r < HDIM) hbuf[0][r] = (_Float16)0.f;
    float c = 0.f;

    const float* xg_ptr = Xg + (size_t)b * NGATE + (size_t)d * G4 + rr;
    const ptrdiff_t sstride = (ptrdiff_t)BATCH * NGATE;

    __syncthreads();

    int tt0 = d ? (SEQ - 1) : 0;
    float xg_c = xg_ptr[(ptrdiff_t)tt0 * sstride];

    const _Float16* hcur = hbuf[0];
    _Float16* hnxt = hbuf[1];

#pragma unroll 1
    for (int t = 0; t < SEQ; ++t) {
        int tt = d ? (SEQ - 1 - t) : t;
        // prefetch next step's Xg element
        float xg_n = 0.f;
        if (t + 1 < SEQ)
            xg_n = xg_ptr[(ptrdiff_t)(d ? (SEQ - 2 - t) : (t + 1)) * sstride];

        float a0 = xg_c, a1 = 0.f;
        // pinned chunks (h broadcast reads: same-address uint4)
#define PDOT(i) { uint4 hv_ = *(const uint4*)&hcur[8 * (i)];                \
                  if ((i) & 1) a1 = dot8(p##i, hv_, a1);                    \
                  else         a0 = dot8(p##i, hv_, a0); }
        REPP(PDOT)
#undef PDOT
        // LDS-resident chunks 16..19
#pragma unroll
        for (int j = 0; j < NLDS; ++j) {
            uint4 uv = *(const uint4*)&lds_u[j][rr][0];
            uint4 hv = *(const uint4*)&hcur[8 * (PERSIST + j)];
            if ((PERSIST + j) & 1) a1 = dot8(uv, hv, a1);
            else                   a0 = dot8(uv, hv, a0);
        }
        // streamed chunks 20..24 from L2 (coalesced across lanes)
#pragma unroll
        for (int kc = STREAM0; kc < KC; ++kc) {
            uint4 uv = *(const uint4*)(up_ptr + (size_t)kc * CHSTRIDE);
            uint4 hv = *(const uint4*)&hcur[8 * kc];
            if (kc & 1) a1 = dot8(uv, hv, a1);
            else        a0 = dot8(uv, hv, a0);
        }
        if (r < G4) g_lds[r] = a0 + a1;
        __syncthreads();

        if (r < HDIM) {
            float gi = g_lds[r];
            float gf = g_lds[HDIM + r];
            float gg = g_lds[2 * HDIM + r];
            float go = g_lds[3 * HDIM + r];
            float si = fast_sigmoid(gi);
            float sf = fast_sigmoid(gf);
            float so = fast_sigmoid(go);
            c = sf * c + si * fast_tanh(gg);
            float hh = so * fast_tanh(c);
            hnxt[r] = (_Float16)hh;
            Hout[((size_t)tt * BATCH + b) * (2 * HDIM) + d * HDIM + r] = hh;
        }
        __syncthreads();

        const _Float16* tmp = hcur; hcur = hnxt; hnxt = (_Float16*)tmp;
        xg_c = xg_n;
    }
}

// ------------------------------------------------------------------
// K6: out[b][s][o] = sigmoid(H1[s][b][:] . Wo[o][:] + bo[o])
// ------------------------------------------------------------------
__global__ void k_out(const float* __restrict__ H1,
                      const float* __restrict__ Wo,
                      const float* __restrict__ bo,
                      float* __restrict__ out)
{
    int idx = blockIdx.x * blockDim.x + threadIdx.x;
    if (idx >= BATCH * SEQ * 17) return;
    int o = idx % 17;
    int bs = idx / 17;
    int b = bs >> 7;      // /128
    int s = bs & 127;
    const float* hrow = H1 + ((size_t)(s * BATCH + b)) * (2 * HDIM);
    const float* wrow = Wo + (size_t)o * (2 * HDIM);
    float acc = bo[o];
#pragma unroll 4
    for (int j = 0; j < 2 * HDIM; ++j) acc += hrow[j] * wrow[j];
    out[idx] = 1.f / (1.f + __expf(-acc));
}

// ------------------------------------------------------------------
extern "C" void kernel_launch(void* const* d_in, const int* in_sizes, int n_in,
                              void* d_out, int out_size, void* d_ws, size_t ws_size,
                              hipStream_t stream)
{
    const int*   words = (const int*)d_in[0];
    // d_in[1] chars, d_in[2] lens: dead code in the reference
    const float* emb   = (const float*)d_in[3];
    // d_in[4..6]: char conv params, dead
    const float* Wih0  = (const float*)d_in[7];
    const float* Whh0  = (const float*)d_in[8];
    const float* b0    = (const float*)d_in[9];
    const float* Wih1  = (const float*)d_in[10];
    const float* Whh1  = (const float*)d_in[11];
    const float* b1    = (const float*)d_in[12];
    const float* Wo    = (const float*)d_in[13];
    const float* bo    = (const float*)d_in[14];
    float* out = (float*)d_out;

    char* ws = (char*)d_ws;
    const size_t X0_OFF = 0;
    const size_t XG_OFF = X0_OFF + (size_t)SEQ * BATCH * EDIM * 4;          // 4.9 MB
    const size_t H0_OFF = XG_OFF + (size_t)SEQ * BATCH * NGATE * 4;         // +26.2 MB
    const size_t H1_OFF = H0_OFF + (size_t)SEQ * BATCH * 2 * HDIM * 4;      // +6.6 MB
    float* X0 = (float*)(ws + X0_OFF);
    float* Xg = (float*)(ws + XG_OFF);
    float* H0 = (float*)(ws + H0_OFF);
    float* H1 = (float*)(ws + H1_OFF);
    // Upk0/Upk1 overlay the X0 region (X0 dead after the layer-0 GEMM).
    _Float16* Upk0 = (_Float16*)(ws + X0_OFF);
    _Float16* Upk1 = Upk0 + (size_t)2 * KC * 800 * 8;

    // 1. gather embeddings -> X0 (S, B, 300)
    k_gather<<<SEQ * BATCH, 128, 0, stream>>>(words, emb, X0);

    // 2. layer-0 input GEMM: Xg = X0 @ Wih0^T + b0   (4096 x 1600, K=300)
    dim3 gemm_grid(NGATE / BN, (SEQ * BATCH) / BM);
    k_gemm_bias<<<gemm_grid, 256, 0, stream>>>(X0, Wih0, b0, Xg,
                                               SEQ * BATCH, NGATE, EDIM);

    // 2b. pack recurrent weights to fp16 (X0 dead from here on)
    int npack = 2 * KC * 800;
    k_pack<<<(npack + 255) / 256, 256, 0, stream>>>(Whh0, Upk0);
    k_pack<<<(npack + 255) / 256, 256, 0, stream>>>(Whh1, Upk1);

    // 3. layer-0 recurrence -> H0 (S, B, 400)
    k_lstm<<<64, 832, 0, stream>>>(Xg, Upk0, H0);

    // 4. layer-1 input GEMM: Xg = H0 @ Wih1^T + b1   (4096 x 1600, K=400)
    k_gemm_bias<<<gemm_grid, 256, 0, stream>>>(H0, Wih1, b1, Xg,
                                               SEQ * BATCH, NGATE, 2 * HDIM);

    // 5. layer-1 recurrence -> H1
    k_lstm<<<64, 832, 0, stream>>>(Xg, Upk1, H1);

    // 6. output head
    int nout = BATCH * SEQ * 17;
    k_out<<<(nout + 255) / 256, 256, 0, stream>>>(H1, Wo, bo, out);
}

// Round 13
// 648.589 us; speedup vs baseline: 1.2081x; 1.2081x over previous
//
#include <hip/hip_runtime.h>
#include <math.h>

#define SEQ 128
#define BATCH 32
#define EDIM 300
#define HDIM 200
#define G4 800      // 4*H
#define NGATE 1600  // 2 dirs * 4 * H
#define KC 25       // 25 chunks of 8 halves = 200 k-values
#define NLDS 12     // chunks held in LDS (153.6 KB, dynamic)
#define CHSTRIDE 6400   // halves between k-chunks in Upk: 800 rows * 8

#define K0PAD 320   // layer-0 GEMM K (300 padded)
#define K1PAD 416   // layer-1 GEMM K (400 padded)

typedef _Float16 h2t __attribute__((ext_vector_type(2)));
typedef _Float16 f16x8 __attribute__((ext_vector_type(8)));
typedef float f32x4 __attribute__((ext_vector_type(4)));

__device__ __forceinline__ h2t u2h(unsigned v) {
    union { unsigned u; h2t h; } c; c.u = v; return c.h;
}

// v_dot2_f32_f16: acc += a.x*b.x + a.y*b.y  (f32 accumulate)
__device__ __forceinline__ float dot2acc(h2t a, h2t b, float c) {
    return __builtin_amdgcn_fdot2(a, b, c, false);
}

// 8 halves x 8 halves -> acc (4 dot2)
__device__ __forceinline__ float dot8(uint4 u, uint4 h, float acc) {
    acc = dot2acc(u2h(u.x), u2h(h.x), acc);
    acc = dot2acc(u2h(u.y), u2h(h.y), acc);
    acc = dot2acc(u2h(u.z), u2h(h.z), acc);
    acc = dot2acc(u2h(u.w), u2h(h.w), acc);
    return acc;
}

__device__ __forceinline__ float fast_sigmoid(float x) {
    return 1.f / (1.f + __expf(-x));
}
__device__ __forceinline__ float fast_tanh(float x) {
    x = fminf(fmaxf(x, -15.f), 15.f);
    float e = __expf(2.f * x);
    return (e - 1.f) / (e + 1.f);
}

// ------------------------------------------------------------------
// K1: embedding gather -> f16, K zero-padded to K0PAD
//   X0h[t*32+b][e] = (f16) emb[words[b][t]][e]  (e<300), 0 for pad
// ------------------------------------------------------------------
__global__ void k_gather(const int* __restrict__ words,
                         const float* __restrict__ emb,
                         _Float16* __restrict__ X0h)
{
    int row = blockIdx.x;          // row = t*32 + b
    int t = row >> 5;
    int b = row & 31;
    int w = words[b * SEQ + t];
    const float* src = emb + (size_t)w * EDIM;
    _Float16* dst = X0h + (size_t)row * K0PAD;
    for (int e = threadIdx.x; e < K0PAD; e += blockDim.x)
        dst[e] = (e < EDIM) ? (_Float16)src[e] : (_Float16)0.f;
}

// ------------------------------------------------------------------
// K1c: cast W (N,K) f32 -> (N,Kpad) f16, zero-padded
// ------------------------------------------------------------------
__global__ void k_castW(const float* __restrict__ W,
                        _Float16* __restrict__ Wh,
                        int N, int K, int Kpad)
{
    int idx = blockIdx.x * blockDim.x + threadIdx.x;
    if (idx >= N * Kpad) return;
    int n = idx / Kpad, k = idx % Kpad;
    Wh[idx] = (k < K) ? (_Float16)W[(size_t)n * K + k] : (_Float16)0.f;
}

// ------------------------------------------------------------------
// K1b: pack Whh (2,800,200) f32 -> Upk fp16, chunk-major coalesced
// ------------------------------------------------------------------
__global__ void k_pack(const float* __restrict__ Whh,
                       _Float16* __restrict__ Upk)
{
    int idx = blockIdx.x * blockDim.x + threadIdx.x;   // (d*KC+kc)*800 + r
    if (idx >= 2 * KC * 800) return;
    int r  = idx % 800;
    int kc = (idx / 800) % KC;
    int d  = idx / (800 * KC);
    const float* src = Whh + ((size_t)d * G4 + r) * HDIM + kc * 8;
    _Float16* dst = Upk + (size_t)idx * 8;
#pragma unroll
    for (int j = 0; j < 8; ++j) dst[j] = (_Float16)src[j];
}

// ------------------------------------------------------------------
// K2/K4: MFMA f16 GEMM:  C[M,N] = A[M,Kpad] @ Bw[N,Kpad]^T + bias[N]
// block 256 thr = 4 waves; tile 64x64, BK=32.
// Wave w: rows w*16..+16, all 64 cols (4 MFMA per K-slice, A-frag shared).
// A/B frag: lane l -> row/col = l&15, k = (l>>4)*8 + j (canonical).
// D frag (guide-verified m89): col = lane&15, row = (lane>>4)*4 + reg.
// LDS rows padded to 40 halves (80 B) to break the 64B-stride conflict.
// ------------------------------------------------------------------
#define GBM 64
#define GBN 64
#define GBK 32
#define GLD 40

__global__ __launch_bounds__(256)
void k_gemm_mfma(const _Float16* __restrict__ A,
                 const _Float16* __restrict__ Bw,
                 const float* __restrict__ bias,
                 float* __restrict__ C,
                 int M, int N, int Kpad)
{
    __shared__ __align__(16) _Float16 As[GBM][GLD];
    __shared__ __align__(16) _Float16 Bs[GBN][GLD];
    int tid = threadIdx.x;
    int wave = tid >> 6;
    int lane = tid & 63;
    int bm = blockIdx.y * GBM, bn = blockIdx.x * GBN;

    int srow = tid >> 2;          // staging: row 0..63
    int sseg = (tid & 3) * 8;     // k-segment 0,8,16,24

    f32x4 acc0 = {0,0,0,0}, acc1 = {0,0,0,0}, acc2 = {0,0,0,0}, acc3 = {0,0,0,0};
    int am = lane & 15;
    int kg = (lane >> 4) * 8;

    for (int k0 = 0; k0 < Kpad; k0 += GBK) {
        *(f16x8*)&As[srow][sseg] = *(const f16x8*)&A[(size_t)(bm + srow) * Kpad + k0 + sseg];
        *(f16x8*)&Bs[srow][sseg] = *(const f16x8*)&Bw[(size_t)(bn + srow) * Kpad + k0 + sseg];
        __syncthreads();
        f16x8 af = *(const f16x8*)&As[wave * 16 + am][kg];
        f16x8 b0 = *(const f16x8*)&Bs[ 0 + am][kg];
        f16x8 b1 = *(const f16x8*)&Bs[16 + am][kg];
        f16x8 b2 = *(const f16x8*)&Bs[32 + am][kg];
        f16x8 b3 = *(const f16x8*)&Bs[48 + am][kg];
        acc0 = __builtin_amdgcn_mfma_f32_16x16x32_f16(af, b0, acc0, 0, 0, 0);
        acc1 = __builtin_amdgcn_mfma_f32_16x16x32_f16(af, b1, acc1, 0, 0, 0);
        acc2 = __builtin_amdgcn_mfma_f32_16x16x32_f16(af, b2, acc2, 0, 0, 0);
        acc3 = __builtin_amdgcn_mfma_f32_16x16x32_f16(af, b3, acc3, 0, 0, 0);
        __syncthreads();
    }
    int col0 = lane & 15;
    int row0 = (lane >> 4) * 4;
#pragma unroll
    for (int r2 = 0; r2 < 4; ++r2) {
        int m = bm + wave * 16 + row0 + r2;
        float* crow = &C[(size_t)m * N + bn];
        crow[ 0 + col0] = acc0[r2] + bias[bn +  0 + col0];
        crow[16 + col0] = acc1[r2] + bias[bn + 16 + col0];
        crow[32 + col0] = acc2[r2] + bias[bn + 32 + col0];
        crow[48 + col0] = acc3[r2] + bias[bn + 48 + col0];
    }
}

// ------------------------------------------------------------------
// K3/K5: recurrent BiLSTM layer.
// U placement: 12 chunks in DYNAMIC LDS (153.6 KB; needs
// hipFuncSetAttribute), 13 streamed from L2 (166 KB/step, ~2400 cyc)
// -- LDS pipe (~2700 cyc) and VMEM pipe overlap. No register pinning
// (R12: pins land in AGPRs, +1 VALU per use -> regression).
// Writes Hout f32 (for k_out) AND Houth f16 (Kpad=416, for the
// layer-1 MFMA GEMM; pad cols zeroed by threads 800..815 of d==0).
// ------------------------------------------------------------------
__global__ __launch_bounds__(832)
void k_lstm(const float* __restrict__ Xg,
            const _Float16* __restrict__ Upk,  // (2, KC, 800, 8) halves
            float* __restrict__ Hout,          // (S, B, 400) f32
            _Float16* __restrict__ Houth)      // (S*B, 416) f16
{
    int blk = blockIdx.x;      // 0..63
    int d = blk >> 5;          // direction
    int b = blk & 31;          // batch
    int r = threadIdx.x;       // gate row
    int rr = (r < G4) ? r : (G4 - 1);   // clamped

    extern __shared__ __align__(16) char smem[];
    _Float16 (*lds_u)[800][8] = (_Float16 (*)[800][8])smem;        // 153600 B
    float* g_lds = (float*)(smem + 153600);                        // 3200 B
    _Float16 (*hbuf)[HDIM] = (_Float16 (*)[HDIM])(smem + 156800);  // 800 B

    const _Float16* up_ptr = Upk + ((size_t)d * KC * 800 + rr) * 8;

    // stage chunks 0..11 into LDS (each worker writes its own row)
    if (r < G4) {
#pragma unroll
        for (int j = 0; j < NLDS; ++j)
            *(uint4*)&lds_u[j][r][0] =
                *(const uint4*)(up_ptr + (size_t)j * CHSTRIDE);
    }

    if (r < HDIM) hbuf[0][r] = (_Float16)0.f;
    float c = 0.f;

    const float* xg_ptr = Xg + (size_t)b * NGATE + (size_t)d * G4 + rr;
    const ptrdiff_t sstride = (ptrdiff_t)BATCH * NGATE;

    __syncthreads();

    int tt0 = d ? (SEQ - 1) : 0;
    float xg_c = xg_ptr[(ptrdiff_t)tt0 * sstride];

    const _Float16* hcur = hbuf[0];
    _Float16* hnxt = hbuf[1];

#pragma unroll 1
    for (int t = 0; t < SEQ; ++t) {
        int tt = d ? (SEQ - 1 - t) : t;
        // prefetch next step's Xg element
        float xg_n = 0.f;
        if (t + 1 < SEQ)
            xg_n = xg_ptr[(ptrdiff_t)(d ? (SEQ - 2 - t) : (t + 1)) * sstride];

        float a0 = xg_c, a1 = 0.f;
        // LDS-resident chunks 0..11 (U row reads + h broadcasts)
#pragma unroll
        for (int kc = 0; kc < NLDS; ++kc) {
            uint4 uv = *(const uint4*)&lds_u[kc][rr][0];
            uint4 hv = *(const uint4*)&hcur[8 * kc];
            if (kc & 1) a1 = dot8(uv, hv, a1);
            else        a0 = dot8(uv, hv, a0);
        }
        // streamed chunks 12..24 from L2 (coalesced across lanes)
#pragma unroll
        for (int kc = NLDS; kc < KC; ++kc) {
            uint4 uv = *(const uint4*)(up_ptr + (size_t)kc * CHSTRIDE);
            uint4 hv = *(const uint4*)&hcur[8 * kc];
            if (kc & 1) a1 = dot8(uv, hv, a1);
            else        a0 = dot8(uv, hv, a0);
        }
        if (r < G4) g_lds[r] = a0 + a1;
        __syncthreads();

        if (r < HDIM) {
            float gi = g_lds[r];
            float gf = g_lds[HDIM + r];
            float gg = g_lds[2 * HDIM + r];
            float go = g_lds[3 * HDIM + r];
            float si = fast_sigmoid(gi);
            float sf = fast_sigmoid(gf);
            float so = fast_sigmoid(go);
            c = sf * c + si * fast_tanh(gg);
            float hh = so * fast_tanh(c);
            hnxt[r] = (_Float16)hh;
            size_t rowi = (size_t)tt * BATCH + b;
            Hout[rowi * (2 * HDIM) + d * HDIM + r] = hh;
            Houth[rowi * K1PAD + d * HDIM + r] = (_Float16)hh;
        } else if (d == 0 && r >= 800 && r < 816) {
            // zero the K-pad columns 400..415 every step (buffers are
            // poisoned; must not rely on prior state)
            Houth[((size_t)tt * BATCH + b) * K1PAD + 400 + (r - 800)] = (_Float16)0.f;
        }
        __syncthreads();

        const _Float16* tmp = hcur; hcur = hnxt; hnxt = (_Float16*)tmp;
        xg_c = xg_n;
    }
}

// ------------------------------------------------------------------
// K6: out[b][s][o] = sigmoid(H1[s][b][:] . Wo[o][:] + bo[o])
// ------------------------------------------------------------------
__global__ void k_out(const float* __restrict__ H1,
                      const float* __restrict__ Wo,
                      const float* __restrict__ bo,
                      float* __restrict__ out)
{
    int idx = blockIdx.x * blockDim.x + threadIdx.x;
    if (idx >= BATCH * SEQ * 17) return;
    int o = idx % 17;
    int bs = idx / 17;
    int b = bs >> 7;      // /128
    int s = bs & 127;
    const float* hrow = H1 + ((size_t)(s * BATCH + b)) * (2 * HDIM);
    const float* wrow = Wo + (size_t)o * (2 * HDIM);
    float acc = bo[o];
#pragma unroll 4
    for (int j = 0; j < 2 * HDIM; ++j) acc += hrow[j] * wrow[j];
    out[idx] = 1.f / (1.f + __expf(-acc));
}

// ------------------------------------------------------------------
extern "C" void kernel_launch(void* const* d_in, const int* in_sizes, int n_in,
                              void* d_out, int out_size, void* d_ws, size_t ws_size,
                              hipStream_t stream)
{
    const int*   words = (const int*)d_in[0];
    // d_in[1] chars, d_in[2] lens: dead code in the reference
    const float* emb   = (const float*)d_in[3];
    // d_in[4..6]: char conv params, dead
    const float* Wih0  = (const float*)d_in[7];
    const float* Whh0  = (const float*)d_in[8];
    const float* b0    = (const float*)d_in[9];
    const float* Wih1  = (const float*)d_in[10];
    const float* Whh1  = (const float*)d_in[11];
    const float* b1    = (const float*)d_in[12];
    const float* Wo    = (const float*)d_in[13];
    const float* bo    = (const float*)d_in[14];
    float* out = (float*)d_out;

    char* ws = (char*)d_ws;
    // layout (bytes):
    const size_t X0H_OFF = 0;                                   // 4096*320*2  = 2,621,440
    const size_t W0H_OFF = X0H_OFF + (size_t)4096 * K0PAD * 2;  // 1600*320*2  = 1,024,000
    const size_t W1H_OFF = W0H_OFF + (size_t)NGATE * K0PAD * 2; // 1600*416*2  = 1,331,200
    const size_t UP0_OFF = W1H_OFF + (size_t)NGATE * K1PAD * 2; // 640,000
    const size_t UP1_OFF = UP0_OFF + (size_t)2 * KC * 800 * 8 * 2;
    const size_t XG_OFF  = UP1_OFF + (size_t)2 * KC * 800 * 8 * 2; // 26,214,400
    const size_t H1_OFF  = XG_OFF + (size_t)SEQ * BATCH * NGATE * 4; // 6,553,600
    const size_t HT0_OFF = H1_OFF + (size_t)SEQ * BATCH * 2 * HDIM * 4; // 4096*416*2
    // total ~42.4 MB (previously-proven ws usage was 44.3 MB)

    _Float16* X0h   = (_Float16*)(ws + X0H_OFF);
    _Float16* W0h   = (_Float16*)(ws + W0H_OFF);
    _Float16* W1h   = (_Float16*)(ws + W1H_OFF);
    _Float16* Upk0  = (_Float16*)(ws + UP0_OFF);
    _Float16* Upk1  = (_Float16*)(ws + UP1_OFF);
    float*    Xg    = (float*)(ws + XG_OFF);
    float*    H1    = (float*)(ws + H1_OFF);
    float*    Hdump = H1;                       // layer-0 f32 out (unused)
    _Float16* Houth0 = (_Float16*)(ws + HT0_OFF);
    _Float16* HouthD = Houth0;                  // layer-1 f16 out (unused, dead region)

    // raise dynamic-LDS cap for k_lstm (157,600 B); host-side attribute,
    // not a stream op -> graph-capture safe
    hipFuncSetAttribute((const void*)k_lstm,
                        hipFuncAttributeMaxDynamicSharedMemorySize, 157600);

    // 1. gather embeddings -> X0h f16 (4096, 320)
    k_gather<<<SEQ * BATCH, 128, 0, stream>>>(words, emb, X0h);

    // 1b. weight casts + recurrent packs
    int ncast0 = NGATE * K0PAD, ncast1 = NGATE * K1PAD;
    k_castW<<<(ncast0 + 255) / 256, 256, 0, stream>>>(Wih0, W0h, NGATE, EDIM, K0PAD);
    k_castW<<<(ncast1 + 255) / 256, 256, 0, stream>>>(Wih1, W1h, NGATE, 2 * HDIM, K1PAD);
    int npack = 2 * KC * 800;
    k_pack<<<(npack + 255) / 256, 256, 0, stream>>>(Whh0, Upk0);
    k_pack<<<(npack + 255) / 256, 256, 0, stream>>>(Whh1, Upk1);

    // 2. layer-0 input GEMM (MFMA): Xg = X0h @ W0h^T + b0
    dim3 ggrid(NGATE / GBN, (SEQ * BATCH) / GBM);
    k_gemm_mfma<<<ggrid, 256, 0, stream>>>(X0h, W0h, b0, Xg,
                                           SEQ * BATCH, NGATE, K0PAD);

    // 3. layer-0 recurrence -> Houth0 (f16) [+ f32 dump]
    k_lstm<<<64, 832, 157600, stream>>>(Xg, Upk0, Hdump, Houth0);

    // 4. layer-1 input GEMM (MFMA): Xg = Houth0 @ W1h^T + b1
    k_gemm_mfma<<<ggrid, 256, 0, stream>>>(Houth0, W1h, b1, Xg,
                                           SEQ * BATCH, NGATE, K1PAD);

    // 5. layer-1 recurrence -> H1 (f32) [+ f16 dump]
    k_lstm<<<64, 832, 157600, stream>>>(Xg, Upk1, H1, HouthD);

    // 6. output head
    int nout = BATCH * SEQ * 17;
    k_out<<<(nout + 255) / 256, 256, 0, stream>>>(H1, Wo, bo, out);
}